// Round 7
// baseline (1068.366 us; speedup 1.0000x reference)
//
#include <hip/hip_runtime.h>

#define B_ 128
#define K_ 25
#define DEG_ 16

#define R4(X) X(0) X(1) X(2) X(3)
#define R8(X) X(0) X(1) X(2) X(3) X(4) X(5) X(6) X(7)

__device__ __forceinline__ float4 f4ma(float t, float4 w, float4 a) {
    a.x = fmaf(t, w.x, a.x); a.y = fmaf(t, w.y, a.y);
    a.z = fmaf(t, w.z, a.z); a.w = fmaf(t, w.w, a.w);
    return a;
}
__device__ __forceinline__ float4 f4max(float4 a, float4 b) {
    return make_float4(fmaxf(a.x, b.x), fmaxf(a.y, b.y), fmaxf(a.z, b.z), fmaxf(a.w, b.w));
}
// bf16 pack/unpack (RTNE)
__device__ __forceinline__ unsigned f2bfu(float f) {
    unsigned u = __float_as_uint(f);
    return (u + 0x7FFFu + ((u >> 16) & 1u)) >> 16;
}
__device__ __forceinline__ unsigned packbf(float e, float o) { return f2bfu(e) | (f2bfu(o) << 16); }
__device__ __forceinline__ float bflo(unsigned u) { return __uint_as_float(u << 16); }
__device__ __forceinline__ float bfhi(unsigned u) { return __uint_as_float(u & 0xFFFF0000u); }

// ---------------- transpose x: (B=128, N=4096) -> x0 (4096, 128)
__global__ __launch_bounds__(256) void k_transpose_x(const float* __restrict__ x, float* __restrict__ x0) {
    int i = blockIdx.x * 256 + threadIdx.x;   // i = v*128 + b
    int v = i >> 7, b = i & 127;
    x0[i] = x[(b << 12) + v];
}

// ---------------- layer-1 SpMM: one wave per row v, lane = float2 column (C=128 -> 64 f2)
__global__ __launch_bounds__(256) void k_spmm1(const int* __restrict__ cols, const float* __restrict__ vals,
        const float2* __restrict__ cur, const float2* __restrict__ prev,
        float2* __restrict__ next, int two) {
    int t = blockIdx.x * 256 + threadIdx.x;
    int v = __builtin_amdgcn_readfirstlane(t >> 6);
    int lane = threadIdx.x & 63;
    int base = v * DEG_;
    float2 s = make_float2(0.f, 0.f);
#pragma unroll
    for (int d = 0; d < DEG_; ++d) {
        float wv = vals[base + d];
        float2 xx = cur[((size_t)cols[base + d] << 6) + lane];
        s.x = fmaf(wv, xx.x, s.x); s.y = fmaf(wv, xx.y, s.y);
    }
    size_t idx = ((size_t)v << 6) + lane;
    if (two) {
        float2 p = prev[idx];
        s.x = 2.f * s.x - p.x; s.y = 2.f * s.y - p.y;
    }
    next[idx] = s;
}

// ---------------- SpMM (layers 2/3) + packed-bf16 mirror write
// XCD slab swizzle, wave-uniform row. Lanes 0-31 carry fi (even), 32-63 fi+1 for same b's;
// shfl_down(32) pairs them; lanes<32 store uint4 of (fi,fi+1) bf16 pairs into [v][fi2][b].
template<int LOGC4>
__global__ __launch_bounds__(256) void k_spmm4(const int* __restrict__ cols, const float* __restrict__ vals,
                        const float4* __restrict__ cur, const float4* __restrict__ prev,
                        float4* __restrict__ next, unsigned* __restrict__ mir, int two) {
    constexpr int LOGW4 = LOGC4 - 3;
    int xcd = blockIdx.x & 7, q = blockIdx.x >> 3;
    int tid = q * 256 + threadIdx.x;
    int v = __builtin_amdgcn_readfirstlane(tid >> LOGW4);
    int c4 = (xcd << LOGW4) + (tid & ((1 << LOGW4) - 1));
    int base = v * DEG_;
    float4 s = make_float4(0.f, 0.f, 0.f, 0.f);
#pragma unroll
    for (int d = 0; d < DEG_; ++d) {
        float w = vals[base + d];
        float4 xx = cur[((size_t)cols[base + d] << LOGC4) + c4];
        s = f4ma(w, xx, s);
    }
    size_t idx = ((size_t)v << LOGC4) + c4;
    if (two) {
        float4 p = prev[idx];
        s.x = 2.f * s.x - p.x; s.y = 2.f * s.y - p.y;
        s.z = 2.f * s.z - p.z; s.w = 2.f * s.w - p.w;
    }
    next[idx] = s;
    float tx = __shfl_down(s.x, 32), ty = __shfl_down(s.y, 32),
          tz = __shfl_down(s.z, 32), tw = __shfl_down(s.w, 32);
    if ((threadIdx.x & 63) < 32) {
        int c = c4 << 2;
        int fi2 = c >> 8, b0 = c & 127;
        uint4 m = make_uint4(packbf(s.x, tx), packbf(s.y, ty), packbf(s.z, tz), packbf(s.w, tw));
        *(uint4*)(mir + ((size_t)v << (LOGC4 + 1)) + ((size_t)fi2 << 7) + b0) = m;
    }
}

// ---------------- layer 1 projection (Fin=1, Fout=32) + bias + relu + pool4 (+ bf16 mirror)
__global__ __launch_bounds__(256) void k_proj1_pool(const float* __restrict__ basis,
        const float* __restrict__ W1, const float* __restrict__ b1, float* __restrict__ pool1,
        unsigned* __restrict__ mir) {
    int half = blockIdx.y;
    int i = blockIdx.x * 256 + threadIdx.x;   // i = g*128 + b
    int g = i >> 7, b = i & 127;
    const float* wbase = W1 + half * 16;
#define P1_DM(j) float4 M##j = make_float4(-1e30f, -1e30f, -1e30f, -1e30f);
    R4(P1_DM)
#undef P1_DM
    for (int r = 0; r < 4; ++r) {
        const float* bp = basis + (((size_t)(4 * g + r) << 7) + b);
#define P1_DC(j) float4 C##j = make_float4(0.f, 0.f, 0.f, 0.f);
        R4(P1_DC)
#undef P1_DC
#pragma unroll 5
        for (int k = 0; k < K_; ++k) {
            float tv = bp[(size_t)k * 524288];
            const float4* w = (const float4*)(wbase + k * 32);
#define P1_FM(j) C##j = f4ma(tv, w[j], C##j);
            R4(P1_FM)
#undef P1_FM
        }
#define P1_MX(j) M##j = f4max(M##j, C##j);
        R4(P1_MX)
#undef P1_MX
    }
    float* op = pool1 + ((size_t)g << 12) + ((size_t)half << 11) + b;
    unsigned* mp = mir + ((size_t)g << 11) + ((size_t)half << 10) + b;
    const float* bb = b1 + half * 16;
#define P1_ST(j) { \
    float e0 = fmaxf(M##j.x + bb[4*j+0], 0.f); \
    float o0 = fmaxf(M##j.y + bb[4*j+1], 0.f); \
    float e1 = fmaxf(M##j.z + bb[4*j+2], 0.f); \
    float o1 = fmaxf(M##j.w + bb[4*j+3], 0.f); \
    op[(4*j+0)*128] = e0; op[(4*j+1)*128] = o0; \
    op[(4*j+2)*128] = e1; op[(4*j+3)*128] = o1; \
    mp[(2*j+0)*128] = packbf(e0, o0); \
    mp[(2*j+1)*128] = packbf(e1, o1); }
    R4(P1_ST)
#undef P1_ST
}

// ---------------- layer-2 chunk projection (bf16 mirror): Fin=32, Fout=64 in 2 slices of 32
// batched loads: 8 mirror dwords in flight, then FMA burst. kcnt fixed = 5.
__global__ __launch_bounds__(256) void k_proj_l2(const unsigned* __restrict__ mir, size_t slotH,
        const float* __restrict__ W, float* __restrict__ acc, int k0, int init,
        const float* __restrict__ bias) {
    int fo0 = blockIdx.y << 5;
    int i = blockIdx.x * 256 + threadIdx.x;   // i = v*128 + b, v in [0,1024)
    int v = i >> 7, b = i & 127;
    float* ap = acc + ((size_t)v << 13) + ((size_t)fo0 << 7) + b;
    const float* bb = bias + fo0;
    float4 A0, A1, A2, A3, A4, A5, A6, A7;
#define L2I(j) if (init) A##j = make_float4(bb[4*j], bb[4*j+1], bb[4*j+2], bb[4*j+3]); \
               else A##j = make_float4(ap[(4*j)*128], ap[(4*j+1)*128], ap[(4*j+2)*128], ap[(4*j+3)*128]);
    R8(L2I)
#undef L2I
    const unsigned* mp0 = mir + ((size_t)v << 11) + b;
    for (int kk = 0; kk < 5; ++kk) {
        const unsigned* mp = mp0 + (size_t)kk * slotH;
        const float* wk = W + (size_t)(k0 + kk) * 64 + fo0;
#pragma unroll
        for (int hh = 0; hh < 2; ++hh) {
            const unsigned* mh = mp + (hh << 10);
            unsigned u0 = mh[0],   u1 = mh[128], u2 = mh[256], u3 = mh[384],
                     u4 = mh[512], u5 = mh[640], u6 = mh[768], u7 = mh[896];
            const float* wh = wk + (size_t)(hh * 16) * 1600;
#define L2S(j) { float fe = bflo(u##j), fd = bfhi(u##j); \
    const float4* we = (const float4*)(wh + (size_t)(2*j) * 1600); \
    const float4* wo = (const float4*)(wh + (size_t)(2*j+1) * 1600); \
    A0=f4ma(fe,we[0],A0); A1=f4ma(fe,we[1],A1); A2=f4ma(fe,we[2],A2); A3=f4ma(fe,we[3],A3); \
    A4=f4ma(fe,we[4],A4); A5=f4ma(fe,we[5],A5); A6=f4ma(fe,we[6],A6); A7=f4ma(fe,we[7],A7); \
    A0=f4ma(fd,wo[0],A0); A1=f4ma(fd,wo[1],A1); A2=f4ma(fd,wo[2],A2); A3=f4ma(fd,wo[3],A3); \
    A4=f4ma(fd,wo[4],A4); A5=f4ma(fd,wo[5],A5); A6=f4ma(fd,wo[6],A6); A7=f4ma(fd,wo[7],A7); }
            R8(L2S)
#undef L2S
        }
    }
#define L2T(j) ap[(4*j)*128]=A##j.x; ap[(4*j+1)*128]=A##j.y; ap[(4*j+2)*128]=A##j.z; ap[(4*j+3)*128]=A##j.w;
    R8(L2T)
#undef L2T
}

// ---------------- layer-3 chunk projection (bf16 mirror): Fin=64, Fout=64,
// 4 fo-slices (grid.y) x 2-way kk-split (grid.z, partial acc1). kcnt fixed = 5 (z0: 0..2, z1: 3..4).
__global__ __launch_bounds__(256) void k_proj_l3(const unsigned* __restrict__ mir, size_t slotH,
        const float* __restrict__ W, float* __restrict__ acc0, float* __restrict__ acc1,
        int k0, int init, const float* __restrict__ bias) {
    int z = blockIdx.z;
    float* accp = z ? acc1 : acc0;
    int fo0 = blockIdx.y << 4;
    int i = blockIdx.x * 256 + threadIdx.x;   // i = v*128 + b, v in [0,256)
    int v = i >> 7, b = i & 127;
    float* ap = accp + ((size_t)v << 13) + ((size_t)fo0 << 7) + b;
    const float* bb = bias + fo0;
    float4 A0, A1, A2, A3;
#define L3I(j) if (init) A##j = z ? make_float4(0.f,0.f,0.f,0.f) \
                                  : make_float4(bb[4*j], bb[4*j+1], bb[4*j+2], bb[4*j+3]); \
               else A##j = make_float4(ap[(4*j)*128], ap[(4*j+1)*128], ap[(4*j+2)*128], ap[(4*j+3)*128]);
    R4(L3I)
#undef L3I
    const unsigned* mp0 = mir + ((size_t)v << 12) + b;
    int kkb = z ? 3 : 0, kke = z ? 5 : 3;
    for (int kk = kkb; kk < kke; ++kk) {
        const unsigned* mp = mp0 + (size_t)kk * slotH;
        const float* wk = W + (size_t)(k0 + kk) * 64 + fo0;
#pragma unroll
        for (int hh = 0; hh < 4; ++hh) {
            const unsigned* mh = mp + (hh << 10);
            unsigned u0 = mh[0],   u1 = mh[128], u2 = mh[256], u3 = mh[384],
                     u4 = mh[512], u5 = mh[640], u6 = mh[768], u7 = mh[896];
            const float* wh = wk + (size_t)(hh * 16) * 1600;
#define L3S(j) { float fe = bflo(u##j), fd = bfhi(u##j); \
    const float4* we = (const float4*)(wh + (size_t)(2*j) * 1600); \
    const float4* wo = (const float4*)(wh + (size_t)(2*j+1) * 1600); \
    A0=f4ma(fe,we[0],A0); A1=f4ma(fe,we[1],A1); A2=f4ma(fe,we[2],A2); A3=f4ma(fe,we[3],A3); \
    A0=f4ma(fd,wo[0],A0); A1=f4ma(fd,wo[1],A1); A2=f4ma(fd,wo[2],A2); A3=f4ma(fd,wo[3],A3); }
            R8(L3S)
#undef L3S
        }
    }
#define L3T(j) ap[(4*j)*128]=A##j.x; ap[(4*j+1)*128]=A##j.y; ap[(4*j+2)*128]=A##j.z; ap[(4*j+3)*128]=A##j.w;
    R4(L3T)
#undef L3T
}

// ---------------- merge kk-split partials + relu: acc0 = max(acc0 + acc1, 0)
__global__ __launch_bounds__(256) void k_l3_merge(float4* __restrict__ a, const float4* __restrict__ p) {
    int i = blockIdx.x * 256 + threadIdx.x;   // 524288 float4
    float4 x = a[i], y = p[i];
    x.x = fmaxf(x.x + y.x, 0.f); x.y = fmaxf(x.y + y.y, 0.f);
    x.z = fmaxf(x.z + y.z, 0.f); x.w = fmaxf(x.w + y.w, 0.f);
    a[i] = x;
}

// ---------------- relu + pool4 + bf16 mirror (layer2 acc -> pool2 + mirror slot0)
__global__ __launch_bounds__(256) void k_relu_pool_m(const float* __restrict__ acc,
        float* __restrict__ pool, unsigned* __restrict__ mir) {
    int i = blockIdx.x * 256 + threadIdx.x;   // g*4096 + fi2*128 + b, total 1,048,576
    int g = i >> 12, fi2 = (i >> 7) & 31, b = i & 127;
    const float* ap = acc + (((size_t)g << 2) << 13) + (fi2 << 8) + b;
    float me = 0.f, mo = 0.f;
#pragma unroll
    for (int r = 0; r < 4; ++r) {
        me = fmaxf(me, ap[0]); mo = fmaxf(mo, ap[128]);
        ap += 8192;
    }
    size_t po = ((size_t)g << 13) + (fi2 << 8) + b;
    pool[po] = me; pool[po + 128] = mo;
    mir[i] = packbf(me, mo);
}

// ---------------- FC1 partials: rowsplit 64, 8 b's per thread, 2048 blocks
__global__ __launch_bounds__(256) void k_fc1_part(const float* __restrict__ t3, const float* __restrict__ w,
                           float* __restrict__ part) {
    int blk = blockIdx.x;
    int bg = blk >> 7;
    int rs = (blk >> 1) & 63;
    int j = ((blk & 1) << 8) + threadIdx.x;
    int b0 = bg << 3;
    float a0=0.f,a1=0.f,a2=0.f,a3=0.f,a4=0.f,a5=0.f,a6=0.f,a7=0.f;
    int r0 = rs << 8;
#pragma unroll 4
    for (int row = r0; row < r0 + 256; ++row) {
        float wv = w[((size_t)row << 9) + j];
        const float4* tp = (const float4*)(t3 + ((size_t)row << 7) + b0);
        float4 t0 = tp[0], t1 = tp[1];
        a0 = fmaf(t0.x, wv, a0);
        a1 = fmaf(t0.y, wv, a1);
        a2 = fmaf(t0.z, wv, a2);
        a3 = fmaf(t0.w, wv, a3);
        a4 = fmaf(t1.x, wv, a4);
        a5 = fmaf(t1.y, wv, a5);
        a6 = fmaf(t1.z, wv, a6);
        a7 = fmaf(t1.w, wv, a7);
    }
    float* pp = part + (((size_t)(rs << 7) + b0) << 9) + j;
    pp[0*512]=a0; pp[1*512]=a1; pp[2*512]=a2; pp[3*512]=a3;
    pp[4*512]=a4; pp[5*512]=a5; pp[6*512]=a6; pp[7*512]=a7;
}

__global__ __launch_bounds__(256) void k_fc1_red(const float* __restrict__ part, const float* __restrict__ bias,
                          float* __restrict__ h) {
    int i = blockIdx.x * 256 + threadIdx.x;   // i = b*512 + j
    float a = bias[i & 511];
#pragma unroll 8
    for (int rs = 0; rs < 64; ++rs) a += part[((size_t)rs << 16) + i];
    h[i] = a;
}

// ---------------- batchnorm stats over batch (biased var), store mean | inv_std
__global__ void k_bnstats(const float* __restrict__ h, float* __restrict__ mv) {
    __shared__ float s1[128], s2[128];
    int j = blockIdx.x, t = threadIdx.x;
    float v = h[(size_t)t * 512 + j];
    s1[t] = v; s2[t] = v * v;
    __syncthreads();
    for (int o = 64; o > 0; o >>= 1) {
        if (t < o) { s1[t] += s1[t + o]; s2[t] += s2[t + o]; }
        __syncthreads();
    }
    if (t == 0) {
        float m = s1[0] * (1.f / 128.f);
        float var = s2[0] * (1.f / 128.f) - m * m;
        mv[j] = m;
        mv[512 + j] = rsqrtf(var + 1e-5f);
    }
}

// ---------------- BN apply + relu + FC2 + log_softmax, one block per batch row
__global__ void k_head(const float* __restrict__ h, const float* __restrict__ mv,
                       const float* __restrict__ gamma, const float* __restrict__ beta,
                       const float* __restrict__ w2, const float* __restrict__ b2,
                       float* __restrict__ out) {
    __shared__ float hr[512];
    __shared__ float lg[16];
    int b = blockIdx.x, t = threadIdx.x;   // 64 threads
    for (int j = t; j < 512; j += 64) {
        float x = (h[(size_t)b * 512 + j] - mv[j]) * mv[512 + j] * gamma[j] + beta[j];
        hr[j] = fmaxf(x, 0.f);
    }
    __syncthreads();
    if (t < 10) {
        float a = b2[t];
        for (int j = 0; j < 512; ++j) a += hr[j] * w2[j * 10 + t];
        lg[t] = a;
    }
    __syncthreads();
    if (t == 0) {
        float mx = -1e30f;
        for (int q = 0; q < 10; ++q) mx = fmaxf(mx, lg[q]);
        float sum = 0.f;
        for (int q = 0; q < 10; ++q) sum += expf(lg[q] - mx);
        float ls = logf(sum) + mx;
        for (int q = 0; q < 10; ++q) out[b * 10 + q] = lg[q] - ls;
    }
}

extern "C" void kernel_launch(void* const* d_in, const int* in_sizes, int n_in,
                              void* d_out, int out_size, void* d_ws, size_t ws_size,
                              hipStream_t stream) {
    (void)in_sizes; (void)n_in; (void)out_size; (void)ws_size;
    const float* x      = (const float*)d_in[0];
    const int*   l0cols = (const int*)d_in[2];
    const float* l0vals = (const float*)d_in[3];
    const int*   l2cols = (const int*)d_in[5];
    const float* l2vals = (const float*)d_in[6];
    const int*   l4cols = (const int*)d_in[8];
    const float* l4vals = (const float*)d_in[9];
    const float* w1   = (const float*)d_in[10];
    const float* b1   = (const float*)d_in[11];
    const float* w2   = (const float*)d_in[12];
    const float* b2   = (const float*)d_in[13];
    const float* w3   = (const float*)d_in[14];
    const float* b3   = (const float*)d_in[15];
    const float* fc1w = (const float*)d_in[16];
    const float* fc1b = (const float*)d_in[17];
    const float* gam  = (const float*)d_in[18];
    const float* bet  = (const float*)d_in[19];
    const float* fc2w = (const float*)d_in[20];
    const float* fc2b = (const float*)d_in[21];
    float* out = (float*)d_out;

    const size_t S1 = 4096 * 128;    // layer-1 basis slot (floats)
    const size_t S2 = 1024 * 4096;   // layer-2 slot (floats); mirror slot = S2/2 dwords
    const size_t S3 = 256 * 8192;    // layer-3 slot (floats); mirror slot = S3/2 dwords
    const int CKP = 5;               // 25 % 5 == 0 -> every proj call has kcnt=5; mirror stays L3-hot

    float* ws = (float*)d_ws;
    float* basis1 = ws;                                  // 25 slots of S1 (layer-1, fp32)
    float* ring2f = ws + 25 * S1;                        // 3 slots S2 (fp32 recursion ring)
    unsigned* mir2 = (unsigned*)(ring2f + 3 * S2);       // CKP slots of S2/2 dwords; also mir3
    float* tailp  = (float*)(mir2 + (size_t)CKP * (S2 / 2));
    float* h      = tailp;
    float* mv     = h + 65536;
    float* acc2   = basis1;                              // 8.39M <= 13.1M, basis1 dead
    float* ring3f = ring2f;                              // 3 slots S3; slot0 = pool2
    float* acc3   = ring2f + 3 * S3;                     // + S3 (z0 partial)
    float* acc3b  = acc3 + S3;                           // + S3 (z1 partial); 5*S3=10.5M <= 3*S2
    unsigned* mir3 = mir2;                               // CKP*S3/2 <= CKP*S2/2
    float* part   = basis1;                              // 4.19M, acc2 dead by then

    // ---------------- Layer 1: V=4096, C=128, full fp32 basis ----------------
    k_transpose_x<<<2048, 256, 0, stream>>>(x, basis1);
    for (int k = 1; k < 25; ++k) {
        const float* cur  = basis1 + (size_t)(k - 1) * S1;
        const float* prev = (k >= 2) ? basis1 + (size_t)(k - 2) * S1 : cur;
        float* next = basis1 + (size_t)k * S1;
        k_spmm1<<<1024, 256, 0, stream>>>(l0cols, l0vals, (const float2*)cur,
                                          (const float2*)prev, (float2*)next, k >= 2 ? 1 : 0);
    }
    // pool1 -> ring2f slot0 (fp32, x0 for recursion) + mir2 slot0 (bf16, for proj)
    k_proj1_pool<<<dim3(512, 2), 256, 0, stream>>>(basis1, w1, b1, ring2f, mir2);

    // ---------------- Layer 2: V=1024, C=4096 ----------------
    {
        int cs = 0;
        for (int k = 0; k < 25; ++k) {
            if (k >= 1) {
                const float* cur  = ring2f + (size_t)((k - 1) % 3) * S2;
                const float* prev = ring2f + (size_t)((k >= 2 ? k - 2 : 0) % 3) * S2;
                float* next = ring2f + (size_t)(k % 3) * S2;
                unsigned* mirp = mir2 + (size_t)(k % CKP) * (S2 / 2);
                k_spmm4<10><<<4096, 256, 0, stream>>>(l2cols, l2vals, (const float4*)cur,
                                                      (const float4*)prev, (float4*)next,
                                                      mirp, k >= 2 ? 1 : 0);
            }
            if (k - cs + 1 == CKP) {
                k_proj_l2<<<dim3(512, 2), 256, 0, stream>>>(mir2, S2 / 2, w2, acc2, cs,
                                                            cs == 0 ? 1 : 0, b2);
                cs = k + 1;
            }
        }
    }
    k_relu_pool_m<<<4096, 256, 0, stream>>>(acc2, ring3f /*pool2 = slot0*/, mir3 /*slot0*/);

    // ---------------- Layer 3: V=256, C=8192 ----------------
    {
        int cs = 0;
        for (int k = 0; k < 25; ++k) {
            if (k >= 1) {
                const float* cur  = ring3f + (size_t)((k - 1) % 3) * S3;
                const float* prev = ring3f + (size_t)((k >= 2 ? k - 2 : 0) % 3) * S3;
                float* next = ring3f + (size_t)(k % 3) * S3;
                unsigned* mirp = mir3 + (size_t)(k % CKP) * (S3 / 2);
                k_spmm4<11><<<2048, 256, 0, stream>>>(l4cols, l4vals, (const float4*)cur,
                                                      (const float4*)prev, (float4*)next,
                                                      mirp, k >= 2 ? 1 : 0);
            }
            if (k - cs + 1 == CKP) {
                k_proj_l3<<<dim3(128, 4, 2), 256, 0, stream>>>(mir3, S3 / 2, w3, acc3, acc3b,
                                                               cs, cs == 0 ? 1 : 0, b3);
                cs = k + 1;
            }
        }
    }
    k_l3_merge<<<2048, 256, 0, stream>>>((float4*)acc3, (const float4*)acc3b);

    // ---------------- FC1 + BN + FC2 + log_softmax ----------------
    k_fc1_part<<<2048, 256, 0, stream>>>(acc3, fc1w, part);
    k_fc1_red<<<256, 256, 0, stream>>>(part, fc1b, h);
    k_bnstats<<<512, 128, 0, stream>>>(h, mv);
    k_head<<<128, 64, 0, stream>>>(h, mv, gam, bet, fc2w, fc2b, out);
}

// Round 9
// 919.002 us; speedup vs baseline: 1.1625x; 1.1625x over previous
//
#include <hip/hip_runtime.h>

#define B_ 128
#define K_ 25
#define DEG_ 16

#define R4(X) X(0) X(1) X(2) X(3)

typedef __attribute__((ext_vector_type(4))) float f32x4;
typedef __attribute__((ext_vector_type(8))) short bf16x8;

__device__ __forceinline__ float4 f4ma(float t, float4 w, float4 a) {
    a.x = fmaf(t, w.x, a.x); a.y = fmaf(t, w.y, a.y);
    a.z = fmaf(t, w.z, a.z); a.w = fmaf(t, w.w, a.w);
    return a;
}
__device__ __forceinline__ float4 f4max(float4 a, float4 b) {
    return make_float4(fmaxf(a.x, b.x), fmaxf(a.y, b.y), fmaxf(a.z, b.z), fmaxf(a.w, b.w));
}
// bf16 pack/unpack (RTNE)
__device__ __forceinline__ unsigned f2bfu(float f) {
    unsigned u = __float_as_uint(f);
    return (u + 0x7FFFu + ((u >> 16) & 1u)) >> 16;
}
__device__ __forceinline__ unsigned packbf(float e, float o) { return f2bfu(e) | (f2bfu(o) << 16); }

__device__ __forceinline__ bf16x8 u2b(uint4 u) {
    union { uint4 u4; bf16x8 b8; } c; c.u4 = u; return c.b8;
}
__device__ __forceinline__ f32x4 mfma_bf(uint4 a, uint4 b, f32x4 c) {
    return __builtin_amdgcn_mfma_f32_16x16x32_bf16(u2b(a), u2b(b), c, 0, 0, 0);
}

// ---------------- transpose x: (B=128, N=4096) -> x0 (4096, 128)
__global__ __launch_bounds__(256) void k_transpose_x(const float* __restrict__ x, float* __restrict__ x0) {
    int i = blockIdx.x * 256 + threadIdx.x;   // i = v*128 + b
    int v = i >> 7, b = i & 127;
    x0[i] = x[(b << 12) + v];
}

// ---------------- prepack W2/W3 -> bf16 [k][fo][fi]
__global__ __launch_bounds__(256) void k_packw(const float* __restrict__ w2, const float* __restrict__ w3,
        unsigned short* __restrict__ wb2, unsigned short* __restrict__ wb3) {
    int i = blockIdx.x * 256 + threadIdx.x;
    if (i < 51200) {        // 25*64*32
        int k = i >> 11, rem = i & 2047, fo = rem >> 5, fi = rem & 31;
        wb2[i] = (unsigned short)f2bfu(w2[(size_t)(fi * K_ + k) * 64 + fo]);
    }
    if (i < 102400) {       // 25*64*64
        int k = i >> 12, rem = i & 4095, fo = rem >> 6, fi = rem & 63;
        wb3[i] = (unsigned short)f2bfu(w3[(size_t)(fi * K_ + k) * 64 + fo]);
    }
}

// ---------------- layer-1 SpMM: one wave per row v, lane = float2 column (C=128 -> 64 f2)
__global__ __launch_bounds__(256) void k_spmm1(const int* __restrict__ cols, const float* __restrict__ vals,
        const float2* __restrict__ cur, const float2* __restrict__ prev,
        float2* __restrict__ next, int two) {
    int t = blockIdx.x * 256 + threadIdx.x;
    int v = __builtin_amdgcn_readfirstlane(t >> 6);
    int lane = threadIdx.x & 63;
    int base = v * DEG_;
    float2 s = make_float2(0.f, 0.f);
#pragma unroll
    for (int d = 0; d < DEG_; ++d) {
        float wv = vals[base + d];
        float2 xx = cur[((size_t)cols[base + d] << 6) + lane];
        s.x = fmaf(wv, xx.x, s.x); s.y = fmaf(wv, xx.y, s.y);
    }
    size_t idx = ((size_t)v << 6) + lane;
    if (two) {
        float2 p = prev[idx];
        s.x = 2.f * s.x - p.x; s.y = 2.f * s.y - p.y;
    }
    next[idx] = s;
}

// ---------------- SpMM (layers 2/3) + packed-bf16 mirror write
template<int LOGC4>
__global__ __launch_bounds__(256) void k_spmm4(const int* __restrict__ cols, const float* __restrict__ vals,
                        const float4* __restrict__ cur, const float4* __restrict__ prev,
                        float4* __restrict__ next, unsigned* __restrict__ mir, int two) {
    constexpr int LOGW4 = LOGC4 - 3;
    int xcd = blockIdx.x & 7, q = blockIdx.x >> 3;
    int tid = q * 256 + threadIdx.x;
    int v = __builtin_amdgcn_readfirstlane(tid >> LOGW4);
    int c4 = (xcd << LOGW4) + (tid & ((1 << LOGW4) - 1));
    int base = v * DEG_;
    float4 s = make_float4(0.f, 0.f, 0.f, 0.f);
#pragma unroll
    for (int d = 0; d < DEG_; ++d) {
        float w = vals[base + d];
        float4 xx = cur[((size_t)cols[base + d] << LOGC4) + c4];
        s = f4ma(w, xx, s);
    }
    size_t idx = ((size_t)v << LOGC4) + c4;
    if (two) {
        float4 p = prev[idx];
        s.x = 2.f * s.x - p.x; s.y = 2.f * s.y - p.y;
        s.z = 2.f * s.z - p.z; s.w = 2.f * s.w - p.w;
    }
    next[idx] = s;
    float tx = __shfl_down(s.x, 32), ty = __shfl_down(s.y, 32),
          tz = __shfl_down(s.z, 32), tw = __shfl_down(s.w, 32);
    if ((threadIdx.x & 63) < 32) {
        int c = c4 << 2;
        int fi2 = c >> 8, b0 = c & 127;
        uint4 m = make_uint4(packbf(s.x, tx), packbf(s.y, ty), packbf(s.z, tz), packbf(s.w, tw));
        *(uint4*)(mir + ((size_t)v << (LOGC4 + 1)) + ((size_t)fi2 << 7) + b0) = m;
    }
}

// ---------------- layer 1 projection (Fin=1, Fout=32) + bias + relu + pool4 (+ bf16 mirror)
__global__ __launch_bounds__(256) void k_proj1_pool(const float* __restrict__ basis,
        const float* __restrict__ W1, const float* __restrict__ b1, float* __restrict__ pool1,
        unsigned* __restrict__ mir) {
    int half = blockIdx.y;
    int i = blockIdx.x * 256 + threadIdx.x;   // i = g*128 + b
    int g = i >> 7, b = i & 127;
    const float* wbase = W1 + half * 16;
#define P1_DM(j) float4 M##j = make_float4(-1e30f, -1e30f, -1e30f, -1e30f);
    R4(P1_DM)
#undef P1_DM
    for (int r = 0; r < 4; ++r) {
        const float* bp = basis + (((size_t)(4 * g + r) << 7) + b);
#define P1_DC(j) float4 C##j = make_float4(0.f, 0.f, 0.f, 0.f);
        R4(P1_DC)
#undef P1_DC
#pragma unroll 5
        for (int k = 0; k < K_; ++k) {
            float tv = bp[(size_t)k * 524288];
            const float4* w = (const float4*)(wbase + k * 32);
#define P1_FM(j) C##j = f4ma(tv, w[j], C##j);
            R4(P1_FM)
#undef P1_FM
        }
#define P1_MX(j) M##j = f4max(M##j, C##j);
        R4(P1_MX)
#undef P1_MX
    }
    float* op = pool1 + ((size_t)g << 12) + ((size_t)half << 11) + b;
    unsigned* mp = mir + ((size_t)g << 11) + ((size_t)half << 10) + b;
    const float* bb = b1 + half * 16;
#define P1_ST(j) { \
    float e0 = fmaxf(M##j.x + bb[4*j+0], 0.f); \
    float o0 = fmaxf(M##j.y + bb[4*j+1], 0.f); \
    float e1 = fmaxf(M##j.z + bb[4*j+2], 0.f); \
    float o1 = fmaxf(M##j.w + bb[4*j+3], 0.f); \
    op[(4*j+0)*128] = e0; op[(4*j+1)*128] = o0; \
    op[(4*j+2)*128] = e1; op[(4*j+3)*128] = o1; \
    mp[(2*j+0)*128] = packbf(e0, o0); \
    mp[(2*j+1)*128] = packbf(e1, o1); }
    R4(P1_ST)
#undef P1_ST
}

// ---------------- layer-2 chunk projection via MFMA: one wave = 16 b x 64 fo, K=5kk*32fi
// mirror [v][fi2][b] dwords is the A-operand; wb = bf16 [k][fo][fi] (uint4 = 8 fi)
__global__ __launch_bounds__(256) void k_proj_l2m(const unsigned* __restrict__ mir, size_t slotH,
        const uint4* __restrict__ wb, float* __restrict__ acc, int k0, int init,
        const float* __restrict__ bias) {
    int wid = blockIdx.x * 4 + (threadIdx.x >> 6);   // 8192 waves
    int lane = threadIdx.x & 63;
    int lm = lane & 15, lg = lane >> 4;
    int v = wid >> 3, b0 = (wid & 7) << 4;
    float* ap = acc + ((size_t)v << 13) + b0 + (lg << 2);
    f32x4 C0, C1, C2, C3;
    if (init) {
        float q0 = bias[lm], q1 = bias[16 + lm], q2 = bias[32 + lm], q3 = bias[48 + lm];
        C0 = f32x4{q0, q0, q0, q0}; C1 = f32x4{q1, q1, q1, q1};
        C2 = f32x4{q2, q2, q2, q2}; C3 = f32x4{q3, q3, q3, q3};
    } else {
        C0 = *(const f32x4*)(ap + (size_t)lm * 128);
        C1 = *(const f32x4*)(ap + (size_t)(16 + lm) * 128);
        C2 = *(const f32x4*)(ap + (size_t)(32 + lm) * 128);
        C3 = *(const f32x4*)(ap + (size_t)(48 + lm) * 128);
    }
    const unsigned* mp0 = mir + ((size_t)v << 11) + (lg << 9) + b0 + lm;
#pragma unroll
    for (int kk = 0; kk < 5; ++kk) {
        const unsigned* mp = mp0 + (size_t)kk * slotH;
        uint4 a = make_uint4(mp[0], mp[128], mp[256], mp[384]);
        int kb = (k0 + kk) << 6;
        uint4 w0 = wb[(kb + lm) * 4 + lg];
        uint4 w1 = wb[(kb + 16 + lm) * 4 + lg];
        uint4 w2 = wb[(kb + 32 + lm) * 4 + lg];
        uint4 w3 = wb[(kb + 48 + lm) * 4 + lg];
        C0 = mfma_bf(a, w0, C0);
        C1 = mfma_bf(a, w1, C1);
        C2 = mfma_bf(a, w2, C2);
        C3 = mfma_bf(a, w3, C3);
    }
    *(f32x4*)(ap + (size_t)lm * 128) = C0;
    *(f32x4*)(ap + (size_t)(16 + lm) * 128) = C1;
    *(f32x4*)(ap + (size_t)(32 + lm) * 128) = C2;
    *(f32x4*)(ap + (size_t)(48 + lm) * 128) = C3;
}

// ---------------- layer-3 chunk projection via MFMA: Fin=64 -> 2 K-steps per kk
__global__ __launch_bounds__(256) void k_proj_l3m(const unsigned* __restrict__ mir, size_t slotH,
        const uint4* __restrict__ wb, float* __restrict__ acc, int k0, int init,
        const float* __restrict__ bias, int finalrelu) {
    int wid = blockIdx.x * 4 + (threadIdx.x >> 6);   // 2048 waves
    int lane = threadIdx.x & 63;
    int lm = lane & 15, lg = lane >> 4;
    int v = wid >> 3, b0 = (wid & 7) << 4;
    float* ap = acc + ((size_t)v << 13) + b0 + (lg << 2);
    f32x4 C0, C1, C2, C3;
    if (init) {
        float q0 = bias[lm], q1 = bias[16 + lm], q2 = bias[32 + lm], q3 = bias[48 + lm];
        C0 = f32x4{q0, q0, q0, q0}; C1 = f32x4{q1, q1, q1, q1};
        C2 = f32x4{q2, q2, q2, q2}; C3 = f32x4{q3, q3, q3, q3};
    } else {
        C0 = *(const f32x4*)(ap + (size_t)lm * 128);
        C1 = *(const f32x4*)(ap + (size_t)(16 + lm) * 128);
        C2 = *(const f32x4*)(ap + (size_t)(32 + lm) * 128);
        C3 = *(const f32x4*)(ap + (size_t)(48 + lm) * 128);
    }
    const unsigned* mp0 = mir + ((size_t)v << 12) + b0 + lm;
#pragma unroll
    for (int kk = 0; kk < 5; ++kk) {
        const unsigned* mp = mp0 + (size_t)kk * slotH;
        int kb = (k0 + kk) << 6;
#pragma unroll
        for (int ks = 0; ks < 2; ++ks) {
            const unsigned* mk = mp + (size_t)((ks << 4) + (lg << 2)) * 128;
            uint4 a = make_uint4(mk[0], mk[128], mk[256], mk[384]);
            int wof = (ks << 2) + lg;
            uint4 w0 = wb[(kb + lm) * 8 + wof];
            uint4 w1 = wb[(kb + 16 + lm) * 8 + wof];
            uint4 w2 = wb[(kb + 32 + lm) * 8 + wof];
            uint4 w3 = wb[(kb + 48 + lm) * 8 + wof];
            C0 = mfma_bf(a, w0, C0);
            C1 = mfma_bf(a, w1, C1);
            C2 = mfma_bf(a, w2, C2);
            C3 = mfma_bf(a, w3, C3);
        }
    }
    if (finalrelu) {
#pragma unroll
        for (int r = 0; r < 4; ++r) {
            C0[r] = fmaxf(C0[r], 0.f); C1[r] = fmaxf(C1[r], 0.f);
            C2[r] = fmaxf(C2[r], 0.f); C3[r] = fmaxf(C3[r], 0.f);
        }
    }
    *(f32x4*)(ap + (size_t)lm * 128) = C0;
    *(f32x4*)(ap + (size_t)(16 + lm) * 128) = C1;
    *(f32x4*)(ap + (size_t)(32 + lm) * 128) = C2;
    *(f32x4*)(ap + (size_t)(48 + lm) * 128) = C3;
}

// ---------------- relu + pool4 + bf16 mirror (layer2 acc -> pool2 + mirror slot0)
__global__ __launch_bounds__(256) void k_relu_pool_m(const float* __restrict__ acc,
        float* __restrict__ pool, unsigned* __restrict__ mir) {
    int i = blockIdx.x * 256 + threadIdx.x;   // g*4096 + fi2*128 + b, total 1,048,576
    int g = i >> 12, fi2 = (i >> 7) & 31, b = i & 127;
    const float* ap = acc + (((size_t)g << 2) << 13) + (fi2 << 8) + b;
    float me = 0.f, mo = 0.f;
#pragma unroll
    for (int r = 0; r < 4; ++r) {
        me = fmaxf(me, ap[0]); mo = fmaxf(mo, ap[128]);
        ap += 8192;
    }
    size_t po = ((size_t)g << 13) + (fi2 << 8) + b;
    pool[po] = me; pool[po + 128] = mo;
    mir[i] = packbf(me, mo);
}

// ---------------- FC1 partials: rowsplit 64, 8 b's per thread, 2048 blocks
__global__ __launch_bounds__(256) void k_fc1_part(const float* __restrict__ t3, const float* __restrict__ w,
                           float* __restrict__ part) {
    int blk = blockIdx.x;
    int bg = blk >> 7;
    int rs = (blk >> 1) & 63;
    int j = ((blk & 1) << 8) + threadIdx.x;
    int b0 = bg << 3;
    float a0=0.f,a1=0.f,a2=0.f,a3=0.f,a4=0.f,a5=0.f,a6=0.f,a7=0.f;
    int r0 = rs << 8;
#pragma unroll 4
    for (int row = r0; row < r0 + 256; ++row) {
        float wv = w[((size_t)row << 9) + j];
        const float4* tp = (const float4*)(t3 + ((size_t)row << 7) + b0);
        float4 t0 = tp[0], t1 = tp[1];
        a0 = fmaf(t0.x, wv, a0);
        a1 = fmaf(t0.y, wv, a1);
        a2 = fmaf(t0.z, wv, a2);
        a3 = fmaf(t0.w, wv, a3);
        a4 = fmaf(t1.x, wv, a4);
        a5 = fmaf(t1.y, wv, a5);
        a6 = fmaf(t1.z, wv, a6);
        a7 = fmaf(t1.w, wv, a7);
    }
    float* pp = part + (((size_t)(rs << 7) + b0) << 9) + j;
    pp[0*512]=a0; pp[1*512]=a1; pp[2*512]=a2; pp[3*512]=a3;
    pp[4*512]=a4; pp[5*512]=a5; pp[6*512]=a6; pp[7*512]=a7;
}

__global__ __launch_bounds__(256) void k_fc1_red(const float* __restrict__ part, const float* __restrict__ bias,
                          float* __restrict__ h) {
    int i = blockIdx.x * 256 + threadIdx.x;   // i = b*512 + j
    float a = bias[i & 511];
#pragma unroll 8
    for (int rs = 0; rs < 64; ++rs) a += part[((size_t)rs << 16) + i];
    h[i] = a;
}

// ---------------- batchnorm stats over batch (biased var), store mean | inv_std
__global__ void k_bnstats(const float* __restrict__ h, float* __restrict__ mv) {
    __shared__ float s1[128], s2[128];
    int j = blockIdx.x, t = threadIdx.x;
    float v = h[(size_t)t * 512 + j];
    s1[t] = v; s2[t] = v * v;
    __syncthreads();
    for (int o = 64; o > 0; o >>= 1) {
        if (t < o) { s1[t] += s1[t + o]; s2[t] += s2[t + o]; }
        __syncthreads();
    }
    if (t == 0) {
        float m = s1[0] * (1.f / 128.f);
        float var = s2[0] * (1.f / 128.f) - m * m;
        mv[j] = m;
        mv[512 + j] = rsqrtf(var + 1e-5f);
    }
}

// ---------------- BN apply + relu + FC2 + log_softmax, one block per batch row
__global__ void k_head(const float* __restrict__ h, const float* __restrict__ mv,
                       const float* __restrict__ gamma, const float* __restrict__ beta,
                       const float* __restrict__ w2, const float* __restrict__ b2,
                       float* __restrict__ out) {
    __shared__ float hr[512];
    __shared__ float lg[16];
    int b = blockIdx.x, t = threadIdx.x;   // 64 threads
    for (int j = t; j < 512; j += 64) {
        float x = (h[(size_t)b * 512 + j] - mv[j]) * mv[512 + j] * gamma[j] + beta[j];
        hr[j] = fmaxf(x, 0.f);
    }
    __syncthreads();
    if (t < 10) {
        float a = b2[t];
        for (int j = 0; j < 512; ++j) a += hr[j] * w2[j * 10 + t];
        lg[t] = a;
    }
    __syncthreads();
    if (t == 0) {
        float mx = -1e30f;
        for (int q = 0; q < 10; ++q) mx = fmaxf(mx, lg[q]);
        float sum = 0.f;
        for (int q = 0; q < 10; ++q) sum += expf(lg[q] - mx);
        float ls = logf(sum) + mx;
        for (int q = 0; q < 10; ++q) out[b * 10 + q] = lg[q] - ls;
    }
}

extern "C" void kernel_launch(void* const* d_in, const int* in_sizes, int n_in,
                              void* d_out, int out_size, void* d_ws, size_t ws_size,
                              hipStream_t stream) {
    (void)in_sizes; (void)n_in; (void)out_size; (void)ws_size;
    const float* x      = (const float*)d_in[0];
    const int*   l0cols = (const int*)d_in[2];
    const float* l0vals = (const float*)d_in[3];
    const int*   l2cols = (const int*)d_in[5];
    const float* l2vals = (const float*)d_in[6];
    const int*   l4cols = (const int*)d_in[8];
    const float* l4vals = (const float*)d_in[9];
    const float* w1   = (const float*)d_in[10];
    const float* b1   = (const float*)d_in[11];
    const float* w2   = (const float*)d_in[12];
    const float* b2   = (const float*)d_in[13];
    const float* w3   = (const float*)d_in[14];
    const float* b3   = (const float*)d_in[15];
    const float* fc1w = (const float*)d_in[16];
    const float* fc1b = (const float*)d_in[17];
    const float* gam  = (const float*)d_in[18];
    const float* bet  = (const float*)d_in[19];
    const float* fc2w = (const float*)d_in[20];
    const float* fc2b = (const float*)d_in[21];
    float* out = (float*)d_out;

    const size_t S1 = 4096 * 128;    // layer-1 basis slot (floats)
    const size_t S2 = 1024 * 4096;   // layer-2 slot (floats); mirror slot = S2/2 dwords
    const size_t S3 = 256 * 8192;    // layer-3 slot (floats); mirror slot = S3/2 dwords
    const int CKP = 5;               // uniform chunks; mirror stays L3-hot

    float* ws = (float*)d_ws;
    float* basis1 = ws;                                  // 25 slots of S1 (layer-1, fp32)
    float* ring2f = ws + 25 * S1;                        // 3 slots S2 (fp32 recursion ring)
    unsigned* mir2 = (unsigned*)(ring2f + 3 * S2);       // CKP slots of S2/2 dwords; also mir3
    float* tailp  = (float*)(mir2 + (size_t)CKP * (S2 / 2));
    float* h      = tailp;                               // 65536
    float* mv     = h + 65536;                           // 1024
    unsigned short* wb2 = (unsigned short*)(mv + 1024);  // 51200 bf16
    unsigned short* wb3 = wb2 + 51200;                   // 102400 bf16
    float* acc2   = basis1;                              // 8.39M <= 13.1M, basis1 dead
    float* ring3f = ring2f;                              // 3 slots S3; slot0 = pool2
    float* acc3   = ring2f + 3 * S3;                     // 4*S3 <= 3*S2
    unsigned* mir3 = mir2;                               // CKP*S3/2 <= CKP*S2/2
    float* part   = basis1;                              // 4.19M, acc2 dead by then

    k_packw<<<400, 256, 0, stream>>>(w2, w3, wb2, wb3);

    // ---------------- Layer 1: V=4096, C=128, full fp32 basis ----------------
    k_transpose_x<<<2048, 256, 0, stream>>>(x, basis1);
    for (int k = 1; k < 25; ++k) {
        const float* cur  = basis1 + (size_t)(k - 1) * S1;
        const float* prev = (k >= 2) ? basis1 + (size_t)(k - 2) * S1 : cur;
        float* next = basis1 + (size_t)k * S1;
        k_spmm1<<<1024, 256, 0, stream>>>(l0cols, l0vals, (const float2*)cur,
                                          (const float2*)prev, (float2*)next, k >= 2 ? 1 : 0);
    }
    // pool1 -> ring2f slot0 (fp32, x0 for recursion) + mir2 slot0 (bf16, for proj)
    k_proj1_pool<<<dim3(512, 2), 256, 0, stream>>>(basis1, w1, b1, ring2f, mir2);

    // ---------------- Layer 2: V=1024, C=4096 ----------------
    {
        int cs = 0;
        for (int k = 0; k < 25; ++k) {
            if (k >= 1) {
                const float* cur  = ring2f + (size_t)((k - 1) % 3) * S2;
                const float* prev = ring2f + (size_t)((k >= 2 ? k - 2 : 0) % 3) * S2;
                float* next = ring2f + (size_t)(k % 3) * S2;
                unsigned* mirp = mir2 + (size_t)(k % CKP) * (S2 / 2);
                k_spmm4<10><<<4096, 256, 0, stream>>>(l2cols, l2vals, (const float4*)cur,
                                                      (const float4*)prev, (float4*)next,
                                                      mirp, k >= 2 ? 1 : 0);
            }
            if (k - cs + 1 == CKP) {
                k_proj_l2m<<<2048, 256, 0, stream>>>(mir2, S2 / 2, (const uint4*)wb2, acc2, cs,
                                                     cs == 0 ? 1 : 0, b2);
                cs = k + 1;
            }
        }
    }
    k_relu_pool_m<<<4096, 256, 0, stream>>>(acc2, ring3f /*pool2 = slot0*/, mir3 /*slot0*/);

    // ---------------- Layer 3: V=256, C=8192 ----------------
    {
        int cs = 0;
        for (int k = 0; k < 25; ++k) {
            if (k >= 1) {
                const float* cur  = ring3f + (size_t)((k - 1) % 3) * S3;
                const float* prev = ring3f + (size_t)((k >= 2 ? k - 2 : 0) % 3) * S3;
                float* next = ring3f + (size_t)(k % 3) * S3;
                unsigned* mirp = mir3 + (size_t)(k % CKP) * (S3 / 2);
                k_spmm4<11><<<2048, 256, 0, stream>>>(l4cols, l4vals, (const float4*)cur,
                                                      (const float4*)prev, (float4*)next,
                                                      mirp, k >= 2 ? 1 : 0);
            }
            if (k - cs + 1 == CKP) {
                k_proj_l3m<<<512, 256, 0, stream>>>(mir3, S3 / 2, (const uint4*)wb3, acc3, cs,
                                                    cs == 0 ? 1 : 0, b3, cs == 20 ? 1 : 0);
                cs = k + 1;
            }
        }
    }

    // ---------------- FC1 + BN + FC2 + log_softmax ----------------
    k_fc1_part<<<2048, 256, 0, stream>>>(acc3, fc1w, part);
    k_fc1_red<<<256, 256, 0, stream>>>(part, fc1b, h);
    k_bnstats<<<512, 128, 0, stream>>>(h, mv);
    k_head<<<128, 64, 0, stream>>>(h, mv, gam, bet, fc2w, fc2b, out);
}